// Round 4
// baseline (494.528 us; speedup 1.0000x reference)
//
#include <hip/hip_runtime.h>

#define N_NODES 100000
#define N_EDGES 1600000
#define INC 128
#define HIDC 128
#define OUTC 64

constexpr int SCAN_CHUNK = 2048;
constexpr int NSB = (N_NODES + SCAN_CHUNK - 1) / SCAN_CHUNK; // 49 blocks
constexpr int NPASS = 8;                                      // one per XCD
constexpr int TRANGE = (N_NODES + NPASS - 1) / NPASS;         // 12500 targets/pass

// ---------------- bf16 helpers ----------------

__device__ __forceinline__ float blo(unsigned u) { return __uint_as_float(u << 16); }
__device__ __forceinline__ float bhi(unsigned u) { return __uint_as_float(u & 0xFFFF0000u); }
__device__ __forceinline__ unsigned pack_bf2(float a, float b) {
    unsigned ua = __float_as_uint(a);
    ua = (ua + 0x7FFFu + ((ua >> 16) & 1u)) >> 16;
    unsigned ub = __float_as_uint(b);
    ub = (ub + 0x7FFFu + ((ub >> 16) & 1u)) >> 16;
    return ua | (ub << 16);
}

// ---------------- small utility kernels ----------------

__global__ void k_zero(int* __restrict__ p, int n) {
    int i = blockIdx.x * 256 + threadIdx.x;
    if (i < n) p[i] = 0;
}

// Per-XCD private degree histograms: pass p = XCD p (blockIdx&7 heuristic)
// reads a DISJOINT eighth of the target stream (once, coalesced, nt so the
// stream doesn't pollute L2) and atomics into its own 400KB hist window.
__global__ void k_count_priv(const int* __restrict__ ei, int* __restrict__ hist) {
    const int pass = blockIdx.x & 7;
    const int bid = blockIdx.x >> 3;
    const int nb = gridDim.x >> 3;
    int* hp = hist + (size_t)pass * N_NODES;
    const int e0 = (int)((long long)pass * N_EDGES / NPASS);
    const int e1 = (int)((long long)(pass + 1) * N_EDGES / NPASS);
    for (int e = e0 + bid * 256 + threadIdx.x; e < e1; e += nb * 256) {
        int t = __builtin_nontemporal_load(ei + N_EDGES + e);
        atomicAdd(&hp[t], 1);
    }
}

// deg = column-sum of the 8 histograms; dinv = rsqrt(deg)
__global__ void k_degsum(const int* __restrict__ hist, int* __restrict__ deg,
                         float* __restrict__ dinv) {
    int i = blockIdx.x * 256 + threadIdx.x;
    if (i < N_NODES) {
        int d = 0;
#pragma unroll
        for (int p = 0; p < NPASS; ++p) d += hist[(size_t)p * N_NODES + i];
        deg[i] = d;
        dinv[i] = (d > 0) ? rsqrtf((float)d) : 0.f;
    }
}

// ---------------- hierarchical exclusive scan of deg -> offs ----------------

__global__ void k_scan_part(const int* __restrict__ deg, int* __restrict__ bsum) {
    __shared__ int sdata[256];
    int base = blockIdx.x * SCAN_CHUNK;
    int s = 0;
    for (int m = 0; m < SCAN_CHUNK / 256; ++m) {
        int i = base + m * 256 + threadIdx.x;
        s += (i < N_NODES) ? deg[i] : 0;
    }
    sdata[threadIdx.x] = s;
    __syncthreads();
    for (int off = 128; off > 0; off >>= 1) {
        if (threadIdx.x < off) sdata[threadIdx.x] += sdata[threadIdx.x + off];
        __syncthreads();
    }
    if (threadIdx.x == 0) bsum[blockIdx.x] = sdata[0];
}

__global__ void k_scan_top(int* __restrict__ bsum, int* __restrict__ offs) {
    int lane = threadIdx.x; // 0..63, one wave
    int v = (lane < NSB) ? bsum[lane] : 0;
    int x = v;
    for (int off = 1; off < 64; off <<= 1) {
        int t = __shfl_up(x, off);
        if (lane >= off) x += t;
    }
    bsum[lane] = x - v;
    if (lane == 63) offs[N_NODES] = x;
}

__global__ void k_scan_write(const int* __restrict__ deg, const int* __restrict__ bsum,
                             int* __restrict__ offs, int* __restrict__ cursor) {
    __shared__ int sdata[256];
    const int PT = SCAN_CHUNK / 256; // 8
    int base = blockIdx.x * SCAN_CHUNK;
    int tb = base + threadIdx.x * PT;
    int loc[PT];
    int s = 0;
    for (int m = 0; m < PT; ++m) {
        int i = tb + m;
        int d = (i < N_NODES) ? deg[i] : 0;
        loc[m] = s;
        s += d;
    }
    sdata[threadIdx.x] = s;
    __syncthreads();
    for (int off = 1; off < 256; off <<= 1) {
        int t = (threadIdx.x >= off) ? sdata[threadIdx.x - off] : 0;
        __syncthreads();
        sdata[threadIdx.x] += t;
        __syncthreads();
    }
    int texcl = sdata[threadIdx.x] - s + bsum[blockIdx.x];
    for (int m = 0; m < PT; ++m) {
        int i = tb + m;
        if (i < N_NODES) {
            int o = texcl + loc[m];
            offs[i] = o;
            cursor[i] = o;
        }
    }
}

// Bucketed CSR placement. nt loads: the 12.8MB edge stream must NOT allocate
// in L2, so the pass's dirty csr_row/cursor lines stay resident until full.
__global__ void k_place8(const int* __restrict__ ei, int* __restrict__ cursor,
                         int* __restrict__ csr_row) {
    const int pass = blockIdx.x & 7;
    const int bid = blockIdx.x >> 3;
    const int nb = gridDim.x >> 3;
    const int lo = pass * TRANGE;
    const int hi = (lo + TRANGE < N_NODES) ? lo + TRANGE : N_NODES;
    for (int e = bid * 256 + threadIdx.x; e < N_EDGES; e += nb * 256) {
        int t = __builtin_nontemporal_load(ei + N_EDGES + e);
        if (t >= lo && t < hi) {
            int src = __builtin_nontemporal_load(ei + e);
            int p = atomicAdd(&cursor[t], 1);
            csr_row[p] = src;
        }
    }
}

// ---------------- dinv-scaled GEMM -> bf16 output ----------------

template <int OUTTOT>
__global__ __launch_bounds__(256) void k_gemm_scaled(const float* __restrict__ X,
                                                     const float* __restrict__ W,
                                                     const float* __restrict__ dinv,
                                                     unsigned short* __restrict__ outb) {
    __shared__ float xs[64][68];
    __shared__ float wsh[64][64];
    const int tid = threadIdx.x;
    const int oq = tid & 15;
    const int nq = tid >> 4;
    const int n0 = blockIdx.x * 64;
    const int fo0 = blockIdx.y * 64;
    float acc[4][4] = {};

    for (int kh = 0; kh < 2; ++kh) {
#pragma unroll
        for (int m = 0; m < 4; ++m) {
            int q = tid + 256 * m;
            int row = q >> 4, kq = q & 15;
            int nn = n0 + row;
            float4 v = make_float4(0.f, 0.f, 0.f, 0.f);
            if (nn < N_NODES)
                v = *reinterpret_cast<const float4*>(X + (size_t)nn * 128 + kh * 64 + kq * 4);
            *reinterpret_cast<float4*>(&xs[row][kq * 4]) = v;
        }
#pragma unroll
        for (int m = 0; m < 4; ++m) {
            int q = tid + 256 * m;
            int row = q >> 4, fq = q & 15;
            float4 v = *reinterpret_cast<const float4*>(W + (size_t)(kh * 64 + row) * OUTTOT +
                                                        fo0 + fq * 4);
            *reinterpret_cast<float4*>(&wsh[row][fq * 4]) = v;
        }
        __syncthreads();
#pragma unroll 16
        for (int k = 0; k < 64; ++k) {
            float4 wv = *reinterpret_cast<const float4*>(&wsh[k][oq * 4]);
#pragma unroll
            for (int j = 0; j < 4; ++j) {
                float xv = xs[nq + 16 * j][k];
                acc[j][0] += xv * wv.x;
                acc[j][1] += xv * wv.y;
                acc[j][2] += xv * wv.z;
                acc[j][3] += xv * wv.w;
            }
        }
        __syncthreads();
    }
#pragma unroll
    for (int j = 0; j < 4; ++j) {
        int nn = n0 + nq + 16 * j;
        if (nn < N_NODES) {
            float s = dinv[nn];
            uint2 pk;
            pk.x = pack_bf2(acc[j][0] * s, acc[j][1] * s);
            pk.y = pack_bf2(acc[j][2] * s, acc[j][3] * s);
            *reinterpret_cast<uint2*>(outb + (size_t)nn * OUTTOT + fo0 + oq * 4) = pk;
        }
    }
}

// ---------------- CSR aggregation over bf16 rows, XCD-partitioned ----------------
// XCD p handles (node range, feature group): grp = p % GROUPS, rng = p / GROUPS.
// Each XCD's compulsory L2 fill is only 1/GROUPS of hs -> lower chip-wide
// fabric traffic. Row segment = GF bf16; LPR lanes x 16B uint4 loads cover it,
// 64/LPR edge slots in flight, unroll-2, shfl_xor cross-slot reduction.

template <int OC, int GROUPS, bool RELU>
__global__ __launch_bounds__(256) void k_aggv(const uint4* __restrict__ hs,
                                              const int* __restrict__ csr_row,
                                              const int* __restrict__ offs,
                                              const float* __restrict__ dinv,
                                              const float* __restrict__ bias,
                                              float* __restrict__ out) {
    constexpr int GF = OC / GROUPS;        // features per group
    constexpr int RQ = OC * 2 / 16;        // uint4 per full row
    constexpr int GQ = GF * 2 / 16;        // uint4 per group segment
    constexpr int LPR = GQ;                // lanes per row-segment
    constexpr int SLOTS = 64 / LPR;        // edge slots per wave
    constexpr int NRANGES = NPASS / GROUPS;
    constexpr int RLEN = (N_NODES + NRANGES - 1) / NRANGES;

    const int pass = blockIdx.x & 7;
    const int grp = pass % GROUPS;
    const int rng = pass / GROUPS;
    const int lo = rng * RLEN;
    const int hi = (lo + RLEN < N_NODES) ? lo + RLEN : N_NODES;
    const int lane = threadIdx.x & 63;
    const int sub = lane / LPR;
    const int q = lane % LPR;
    const int lwid = (blockIdx.x >> 3) * 4 + (threadIdx.x >> 6);
    const int nlw = (gridDim.x >> 3) * 4;

    for (int t = lo + lwid; t < hi; t += nlw) {
        const int s = offs[t], e2 = offs[t + 1];
        float acc[8] = {0.f, 0.f, 0.f, 0.f, 0.f, 0.f, 0.f, 0.f};
        for (int j = s; j < e2; j += 2 * SLOTS) {
            const int j0 = j + sub, j1 = j + SLOTS + sub;
            const int r0 = (j0 < e2) ? csr_row[j0] : -1;
            const int r1 = (j1 < e2) ? csr_row[j1] : -1;
            uint4 v0 = make_uint4(0u, 0u, 0u, 0u), v1 = v0;
            if (r0 >= 0) v0 = hs[(size_t)r0 * RQ + grp * GQ + q];
            if (r1 >= 0) v1 = hs[(size_t)r1 * RQ + grp * GQ + q];
            acc[0] += blo(v0.x) + blo(v1.x);
            acc[1] += bhi(v0.x) + bhi(v1.x);
            acc[2] += blo(v0.y) + blo(v1.y);
            acc[3] += bhi(v0.y) + bhi(v1.y);
            acc[4] += blo(v0.z) + blo(v1.z);
            acc[5] += bhi(v0.z) + bhi(v1.z);
            acc[6] += blo(v0.w) + blo(v1.w);
            acc[7] += bhi(v0.w) + bhi(v1.w);
        }
#pragma unroll
        for (int off = 32; off >= LPR; off >>= 1) {
#pragma unroll
            for (int i = 0; i < 8; ++i) acc[i] += __shfl_xor(acc[i], off);
        }
        if (lane < LPR) {
            const float dt = dinv[t];
            const float* bp = bias + grp * GF + lane * 8;
            const float4 b0 = *reinterpret_cast<const float4*>(bp);
            const float4 b1 = *reinterpret_cast<const float4*>(bp + 4);
            float4 r0, r1;
            r0.x = acc[0] * dt + b0.x;
            r0.y = acc[1] * dt + b0.y;
            r0.z = acc[2] * dt + b0.z;
            r0.w = acc[3] * dt + b0.w;
            r1.x = acc[4] * dt + b1.x;
            r1.y = acc[5] * dt + b1.y;
            r1.z = acc[6] * dt + b1.z;
            r1.w = acc[7] * dt + b1.w;
            if (RELU) {
                r0.x = fmaxf(r0.x, 0.f); r0.y = fmaxf(r0.y, 0.f);
                r0.z = fmaxf(r0.z, 0.f); r0.w = fmaxf(r0.w, 0.f);
                r1.x = fmaxf(r1.x, 0.f); r1.y = fmaxf(r1.y, 0.f);
                r1.z = fmaxf(r1.z, 0.f); r1.w = fmaxf(r1.w, 0.f);
            }
            float* po = out + (size_t)t * OC + grp * GF + lane * 8;
            *reinterpret_cast<float4*>(po) = r0;
            *reinterpret_cast<float4*>(po + 4) = r1;
        }
    }
}

// ---------------- launch ----------------

extern "C" void kernel_launch(void* const* d_in, const int* in_sizes, int n_in,
                              void* d_out, int out_size, void* d_ws, size_t ws_size,
                              hipStream_t stream) {
    const float* x  = (const float*)d_in[0];
    const int*   ei = (const int*)d_in[1];
    const float* W1 = (const float*)d_in[2];
    const float* b1 = (const float*)d_in[3];
    const float* W2 = (const float*)d_in[4];
    const float* b2 = (const float*)d_in[5];
    float* out = (float*)d_out;

    char* w = (char*)d_ws;
    auto alloc = [&](size_t bytes) {
        void* p = (void*)w;
        w += (bytes + 255) & ~(size_t)255;
        return p;
    };
    int*   deg     = (int*)alloc((size_t)N_NODES * 4);
    float* dinv    = (float*)alloc((size_t)N_NODES * 4);
    int*   offs    = (int*)alloc((size_t)(N_NODES + 1) * 4);
    int*   cursor  = (int*)alloc((size_t)N_NODES * 4);
    int*   bsum    = (int*)alloc(64 * 4);
    int*   hist    = (int*)alloc((size_t)NPASS * N_NODES * 4);
    int*   csr_row = (int*)alloc((size_t)N_EDGES * 4);
    unsigned short* hs1 = (unsigned short*)alloc((size_t)N_NODES * HIDC * 2); // bf16
    float* h       = (float*)alloc((size_t)N_NODES * HIDC * 4);
    unsigned short* hs2 = hs1; // bf16, reuse (hs1 dead after layer-1 agg)

    // CSR + norm build
    k_zero<<<(NPASS * N_NODES + 255) / 256, 256, 0, stream>>>(hist, NPASS * N_NODES);
    k_count_priv<<<3072, 256, 0, stream>>>(ei, hist);
    k_degsum<<<(N_NODES + 255) / 256, 256, 0, stream>>>(hist, deg, dinv);
    k_scan_part<<<NSB, 256, 0, stream>>>(deg, bsum);
    k_scan_top<<<1, 64, 0, stream>>>(bsum, offs);
    k_scan_write<<<NSB, 256, 0, stream>>>(deg, bsum, offs, cursor);
    k_place8<<<3072, 256, 0, stream>>>(ei, cursor, csr_row);

    // layer 1
    dim3 g1((N_NODES + 63) / 64, HIDC / 64);
    k_gemm_scaled<HIDC><<<g1, 256, 0, stream>>>(x, W1, dinv, hs1);
    k_aggv<HIDC, 2, true><<<2048, 256, 0, stream>>>((const uint4*)hs1, csr_row, offs, dinv, b1, h);

    // layer 2
    dim3 g2((N_NODES + 63) / 64, OUTC / 64);
    k_gemm_scaled<OUTC><<<g2, 256, 0, stream>>>(h, W2, dinv, hs2);
    k_aggv<OUTC, 2, false><<<2048, 256, 0, stream>>>((const uint4*)hs2, csr_row, offs, dinv, b2, out);
}

// Round 6
// 453.044 us; speedup vs baseline: 1.0916x; 1.0916x over previous
//
#include <hip/hip_runtime.h>

#define N_NODES 100000
#define N_EDGES 1600000
#define INC 128
#define HIDC 128
#define OUTC 64

constexpr int SCAN_CHUNK = 2048;
constexpr int NSB = (N_NODES + SCAN_CHUNK - 1) / SCAN_CHUNK; // 49 blocks
constexpr int NPASS = 8;                                      // one per XCD
constexpr int TRANGE = (N_NODES + NPASS - 1) / NPASS;         // 12500 targets/pass

// ---------------- bf16 helpers ----------------

__device__ __forceinline__ float blo(unsigned u) { return __uint_as_float(u << 16); }
__device__ __forceinline__ float bhi(unsigned u) { return __uint_as_float(u & 0xFFFF0000u); }
__device__ __forceinline__ unsigned pack_bf2(float a, float b) {
    unsigned ua = __float_as_uint(a);
    ua = (ua + 0x7FFFu + ((ua >> 16) & 1u)) >> 16;
    unsigned ub = __float_as_uint(b);
    ub = (ub + 0x7FFFu + ((ub >> 16) & 1u)) >> 16;
    return ua | (ub << 16);
}

// ---------------- small utility kernels ----------------

__global__ void k_zero(int* __restrict__ p, int n) {
    int i = blockIdx.x * 256 + threadIdx.x;
    if (i < n) p[i] = 0;
}

// Per-XCD private degree histograms over DISJOINT edge ranges; nt stream read.
__global__ void k_count_priv(const int* __restrict__ ei, int* __restrict__ hist) {
    const int pass = blockIdx.x & 7;
    const int bid = blockIdx.x >> 3;
    const int nb = gridDim.x >> 3;
    int* hp = hist + (size_t)pass * N_NODES;
    const int e0 = (int)((long long)pass * N_EDGES / NPASS);
    const int e1 = (int)((long long)(pass + 1) * N_EDGES / NPASS);
    for (int e = e0 + bid * 256 + threadIdx.x; e < e1; e += nb * 256) {
        int t = __builtin_nontemporal_load(ei + N_EDGES + e);
        atomicAdd(&hp[t], 1);
    }
}

// deg = column-sum of the 8 histograms; dinv = rsqrt(deg)
__global__ void k_degsum(const int* __restrict__ hist, int* __restrict__ deg,
                         float* __restrict__ dinv) {
    int i = blockIdx.x * 256 + threadIdx.x;
    if (i < N_NODES) {
        int d = 0;
#pragma unroll
        for (int p = 0; p < NPASS; ++p) d += hist[(size_t)p * N_NODES + i];
        deg[i] = d;
        dinv[i] = (d > 0) ? rsqrtf((float)d) : 0.f;
    }
}

// ---------------- hierarchical exclusive scan of deg -> offs ----------------

__global__ void k_scan_part(const int* __restrict__ deg, int* __restrict__ bsum) {
    __shared__ int sdata[256];
    int base = blockIdx.x * SCAN_CHUNK;
    int s = 0;
    for (int m = 0; m < SCAN_CHUNK / 256; ++m) {
        int i = base + m * 256 + threadIdx.x;
        s += (i < N_NODES) ? deg[i] : 0;
    }
    sdata[threadIdx.x] = s;
    __syncthreads();
    for (int off = 128; off > 0; off >>= 1) {
        if (threadIdx.x < off) sdata[threadIdx.x] += sdata[threadIdx.x + off];
        __syncthreads();
    }
    if (threadIdx.x == 0) bsum[blockIdx.x] = sdata[0];
}

__global__ void k_scan_top(int* __restrict__ bsum, int* __restrict__ offs) {
    int lane = threadIdx.x; // 0..63, one wave
    int v = (lane < NSB) ? bsum[lane] : 0;
    int x = v;
    for (int off = 1; off < 64; off <<= 1) {
        int t = __shfl_up(x, off);
        if (lane >= off) x += t;
    }
    bsum[lane] = x - v;
    if (lane == 63) offs[N_NODES] = x;
}

__global__ void k_scan_write(const int* __restrict__ deg, const int* __restrict__ bsum,
                             int* __restrict__ offs, int* __restrict__ cursor) {
    __shared__ int sdata[256];
    const int PT = SCAN_CHUNK / 256; // 8
    int base = blockIdx.x * SCAN_CHUNK;
    int tb = base + threadIdx.x * PT;
    int loc[PT];
    int s = 0;
    for (int m = 0; m < PT; ++m) {
        int i = tb + m;
        int d = (i < N_NODES) ? deg[i] : 0;
        loc[m] = s;
        s += d;
    }
    sdata[threadIdx.x] = s;
    __syncthreads();
    for (int off = 1; off < 256; off <<= 1) {
        int t = (threadIdx.x >= off) ? sdata[threadIdx.x - off] : 0;
        __syncthreads();
        sdata[threadIdx.x] += t;
        __syncthreads();
    }
    int texcl = sdata[threadIdx.x] - s + bsum[blockIdx.x];
    for (int m = 0; m < PT; ++m) {
        int i = tb + m;
        if (i < N_NODES) {
            int o = texcl + loc[m];
            offs[i] = o;
            cursor[i] = o;
        }
    }
}

// Bucketed CSR placement; nt loads keep the 12.8MB edge stream out of L2 so
// the pass's dirty csr_row/cursor lines stay resident until full.
__global__ void k_place8(const int* __restrict__ ei, int* __restrict__ cursor,
                         int* __restrict__ csr_row) {
    const int pass = blockIdx.x & 7;
    const int bid = blockIdx.x >> 3;
    const int nb = gridDim.x >> 3;
    const int lo = pass * TRANGE;
    const int hi = (lo + TRANGE < N_NODES) ? lo + TRANGE : N_NODES;
    for (int e = bid * 256 + threadIdx.x; e < N_EDGES; e += nb * 256) {
        int t = __builtin_nontemporal_load(ei + N_EDGES + e);
        if (t >= lo && t < hi) {
            int src = __builtin_nontemporal_load(ei + e);
            int p = atomicAdd(&cursor[t], 1);
            csr_row[p] = src;
        }
    }
}

// ---------------- dinv-scaled GEMM -> bf16 output ----------------

template <int OUTTOT>
__global__ __launch_bounds__(256) void k_gemm_scaled(const float* __restrict__ X,
                                                     const float* __restrict__ W,
                                                     const float* __restrict__ dinv,
                                                     unsigned short* __restrict__ outb) {
    __shared__ float xs[64][68];
    __shared__ float wsh[64][64];
    const int tid = threadIdx.x;
    const int oq = tid & 15;
    const int nq = tid >> 4;
    const int n0 = blockIdx.x * 64;
    const int fo0 = blockIdx.y * 64;
    float acc[4][4] = {};

    for (int kh = 0; kh < 2; ++kh) {
#pragma unroll
        for (int m = 0; m < 4; ++m) {
            int q = tid + 256 * m;
            int row = q >> 4, kq = q & 15;
            int nn = n0 + row;
            float4 v = make_float4(0.f, 0.f, 0.f, 0.f);
            if (nn < N_NODES)
                v = *reinterpret_cast<const float4*>(X + (size_t)nn * 128 + kh * 64 + kq * 4);
            *reinterpret_cast<float4*>(&xs[row][kq * 4]) = v;
        }
#pragma unroll
        for (int m = 0; m < 4; ++m) {
            int q = tid + 256 * m;
            int row = q >> 4, fq = q & 15;
            float4 v = *reinterpret_cast<const float4*>(W + (size_t)(kh * 64 + row) * OUTTOT +
                                                        fo0 + fq * 4);
            *reinterpret_cast<float4*>(&wsh[row][fq * 4]) = v;
        }
        __syncthreads();
#pragma unroll 16
        for (int k = 0; k < 64; ++k) {
            float4 wv = *reinterpret_cast<const float4*>(&wsh[k][oq * 4]);
#pragma unroll
            for (int j = 0; j < 4; ++j) {
                float xv = xs[nq + 16 * j][k];
                acc[j][0] += xv * wv.x;
                acc[j][1] += xv * wv.y;
                acc[j][2] += xv * wv.z;
                acc[j][3] += xv * wv.w;
            }
        }
        __syncthreads();
    }
#pragma unroll
    for (int j = 0; j < 4; ++j) {
        int nn = n0 + nq + 16 * j;
        if (nn < N_NODES) {
            float s = dinv[nn];
            uint2 pk;
            pk.x = pack_bf2(acc[j][0] * s, acc[j][1] * s);
            pk.y = pack_bf2(acc[j][2] * s, acc[j][3] * s);
            *reinterpret_cast<uint2*>(outb + (size_t)nn * OUTTOT + fo0 + oq * 4) = pk;
        }
    }
}

// ---------------- CSR aggregation over bf16 rows, latency-optimized ----------------
// One wave per node (grid-stride). LPR lanes cover the row with 16B uint4
// loads; SLOTS edge slots in parallel; U gathers in flight per lane (all
// indices loaded nt before any gather each iteration). Cross-slot shfl_xor
// reduction; fp32 bias/relu/store.

template <int OC, int U, bool RELU>
__global__ __launch_bounds__(256) void k_aggv(const uint4* __restrict__ hs,
                                              const int* __restrict__ csr_row,
                                              const int* __restrict__ offs,
                                              const float* __restrict__ dinv,
                                              const float* __restrict__ bias,
                                              float* __restrict__ out) {
    constexpr int LPR = (OC * 2) / 16;   // 16 (OC=128) or 8 (OC=64)
    constexpr int SLOTS = 64 / LPR;      // 4 or 8
    const int lane = threadIdx.x & 63;
    const int sub = lane / LPR;
    const int q = lane % LPR;
    const int wid = (blockIdx.x * 4) + (threadIdx.x >> 6);
    const int nwaves = gridDim.x * 4;

    for (int t = wid; t < N_NODES; t += nwaves) {
        const int s = offs[t], e2 = offs[t + 1];
        float acc[8] = {0.f, 0.f, 0.f, 0.f, 0.f, 0.f, 0.f, 0.f};
        for (int j = s; j < e2; j += U * SLOTS) {
            int rr[U];
#pragma unroll
            for (int u = 0; u < U; ++u) {
                int jj = j + u * SLOTS + sub;
                rr[u] = (jj < e2) ? __builtin_nontemporal_load(csr_row + jj) : -1;
            }
            uint4 vv[U];
#pragma unroll
            for (int u = 0; u < U; ++u) {
                vv[u] = make_uint4(0u, 0u, 0u, 0u);
                if (rr[u] >= 0) vv[u] = hs[(size_t)rr[u] * LPR + q];
            }
#pragma unroll
            for (int u = 0; u < U; ++u) {
                acc[0] += blo(vv[u].x);
                acc[1] += bhi(vv[u].x);
                acc[2] += blo(vv[u].y);
                acc[3] += bhi(vv[u].y);
                acc[4] += blo(vv[u].z);
                acc[5] += bhi(vv[u].z);
                acc[6] += blo(vv[u].w);
                acc[7] += bhi(vv[u].w);
            }
        }
#pragma unroll
        for (int off = 32; off >= LPR; off >>= 1) {
#pragma unroll
            for (int i = 0; i < 8; ++i) acc[i] += __shfl_xor(acc[i], off);
        }
        if (lane < LPR) {
            const float dt = dinv[t];
            const float4 b0 = *reinterpret_cast<const float4*>(bias + lane * 8);
            const float4 b1 = *reinterpret_cast<const float4*>(bias + lane * 8 + 4);
            float4 r0, r1;
            r0.x = acc[0] * dt + b0.x;
            r0.y = acc[1] * dt + b0.y;
            r0.z = acc[2] * dt + b0.z;
            r0.w = acc[3] * dt + b0.w;
            r1.x = acc[4] * dt + b1.x;
            r1.y = acc[5] * dt + b1.y;
            r1.z = acc[6] * dt + b1.z;
            r1.w = acc[7] * dt + b1.w;
            if (RELU) {
                r0.x = fmaxf(r0.x, 0.f); r0.y = fmaxf(r0.y, 0.f);
                r0.z = fmaxf(r0.z, 0.f); r0.w = fmaxf(r0.w, 0.f);
                r1.x = fmaxf(r1.x, 0.f); r1.y = fmaxf(r1.y, 0.f);
                r1.z = fmaxf(r1.z, 0.f); r1.w = fmaxf(r1.w, 0.f);
            }
            float* po = out + (size_t)t * OC + lane * 8;
            *reinterpret_cast<float4*>(po) = r0;
            *reinterpret_cast<float4*>(po + 4) = r1;
        }
    }
}

// ---------------- launch ----------------

extern "C" void kernel_launch(void* const* d_in, const int* in_sizes, int n_in,
                              void* d_out, int out_size, void* d_ws, size_t ws_size,
                              hipStream_t stream) {
    const float* x  = (const float*)d_in[0];
    const int*   ei = (const int*)d_in[1];
    const float* W1 = (const float*)d_in[2];
    const float* b1 = (const float*)d_in[3];
    const float* W2 = (const float*)d_in[4];
    const float* b2 = (const float*)d_in[5];
    float* out = (float*)d_out;

    char* w = (char*)d_ws;
    auto alloc = [&](size_t bytes) {
        void* p = (void*)w;
        w += (bytes + 255) & ~(size_t)255;
        return p;
    };
    int*   deg     = (int*)alloc((size_t)N_NODES * 4);
    float* dinv    = (float*)alloc((size_t)N_NODES * 4);
    int*   offs    = (int*)alloc((size_t)(N_NODES + 1) * 4);
    int*   cursor  = (int*)alloc((size_t)N_NODES * 4);
    int*   bsum    = (int*)alloc(64 * 4);
    int*   hist    = (int*)alloc((size_t)NPASS * N_NODES * 4);
    int*   csr_row = (int*)alloc((size_t)N_EDGES * 4);
    unsigned short* hs1 = (unsigned short*)alloc((size_t)N_NODES * HIDC * 2); // bf16
    float* h       = (float*)alloc((size_t)N_NODES * HIDC * 4);
    unsigned short* hs2 = hs1; // bf16, reuse (hs1 dead after layer-1 agg)

    // CSR + norm build
    k_zero<<<(NPASS * N_NODES + 255) / 256, 256, 0, stream>>>(hist, NPASS * N_NODES);
    k_count_priv<<<3072, 256, 0, stream>>>(ei, hist);
    k_degsum<<<(N_NODES + 255) / 256, 256, 0, stream>>>(hist, deg, dinv);
    k_scan_part<<<NSB, 256, 0, stream>>>(deg, bsum);
    k_scan_top<<<1, 64, 0, stream>>>(bsum, offs);
    k_scan_write<<<NSB, 256, 0, stream>>>(deg, bsum, offs, cursor);
    k_place8<<<3072, 256, 0, stream>>>(ei, cursor, csr_row);

    // layer 1
    dim3 g1((N_NODES + 63) / 64, HIDC / 64);
    k_gemm_scaled<HIDC><<<g1, 256, 0, stream>>>(x, W1, dinv, hs1);
    k_aggv<HIDC, 4, true><<<2048, 256, 0, stream>>>((const uint4*)hs1, csr_row, offs, dinv, b1, h);

    // layer 2
    dim3 g2((N_NODES + 63) / 64, OUTC / 64);
    k_gemm_scaled<OUTC><<<g2, 256, 0, stream>>>(h, W2, dinv, hs2);
    k_aggv<OUTC, 2, false><<<2048, 256, 0, stream>>>((const uint4*)hs2, csr_row, offs, dinv, b2, out);
}

// Round 7
// 421.005 us; speedup vs baseline: 1.1746x; 1.0761x over previous
//
#include <hip/hip_runtime.h>

#define N_NODES 100000
#define N_EDGES 1600000
#define INC 128
#define HIDC 128
#define OUTC 64

constexpr int SCAN_CHUNK = 2048;
constexpr int NSB = (N_NODES + SCAN_CHUNK - 1) / SCAN_CHUNK; // 49 blocks
constexpr int NPASS = 8;                                      // one per XCD

// Binned scatter geometry: bucket = target >> 9 (512 targets/bucket)
constexpr int BSH = 9;
constexpr int BTGT = 1 << BSH;                                // 512
constexpr int NBUCK = (N_NODES + BTGT - 1) / BTGT;            // 196
constexpr int BIN_TILE = 2048;
constexpr int BIN_EPT = BIN_TILE / 256;                       // 8
constexpr int NBINBLK = (N_EDGES + BIN_TILE - 1) / BIN_TILE;  // 782

// ---------------- bf16 helpers ----------------

__device__ __forceinline__ float blo(unsigned u) { return __uint_as_float(u << 16); }
__device__ __forceinline__ float bhi(unsigned u) { return __uint_as_float(u & 0xFFFF0000u); }
__device__ __forceinline__ unsigned pack_bf2(float a, float b) {
    unsigned ua = __float_as_uint(a);
    ua = (ua + 0x7FFFu + ((ua >> 16) & 1u)) >> 16;
    unsigned ub = __float_as_uint(b);
    ub = (ub + 0x7FFFu + ((ub >> 16) & 1u)) >> 16;
    return ua | (ub << 16);
}

// ---------------- small utility kernels ----------------

__global__ void k_zero(int* __restrict__ p, int n) {
    int i = blockIdx.x * 256 + threadIdx.x;
    if (i < n) p[i] = 0;
}

// Per-XCD private degree histograms over DISJOINT edge ranges; nt stream read.
__global__ void k_count_priv(const int* __restrict__ ei, int* __restrict__ hist) {
    const int pass = blockIdx.x & 7;
    const int bid = blockIdx.x >> 3;
    const int nb = gridDim.x >> 3;
    int* hp = hist + (size_t)pass * N_NODES;
    const int e0 = (int)((long long)pass * N_EDGES / NPASS);
    const int e1 = (int)((long long)(pass + 1) * N_EDGES / NPASS);
    for (int e = e0 + bid * 256 + threadIdx.x; e < e1; e += nb * 256) {
        int t = __builtin_nontemporal_load(ei + N_EDGES + e);
        atomicAdd(&hp[t], 1);
    }
}

// deg = column-sum of the 8 histograms; dinv = rsqrt(deg)
__global__ void k_degsum(const int* __restrict__ hist, int* __restrict__ deg,
                         float* __restrict__ dinv) {
    int i = blockIdx.x * 256 + threadIdx.x;
    if (i < N_NODES) {
        int d = 0;
#pragma unroll
        for (int p = 0; p < NPASS; ++p) d += hist[(size_t)p * N_NODES + i];
        deg[i] = d;
        dinv[i] = (d > 0) ? rsqrtf((float)d) : 0.f;
    }
}

// ---------------- hierarchical exclusive scan of deg -> offs ----------------

__global__ void k_scan_part(const int* __restrict__ deg, int* __restrict__ bsum) {
    __shared__ int sdata[256];
    int base = blockIdx.x * SCAN_CHUNK;
    int s = 0;
    for (int m = 0; m < SCAN_CHUNK / 256; ++m) {
        int i = base + m * 256 + threadIdx.x;
        s += (i < N_NODES) ? deg[i] : 0;
    }
    sdata[threadIdx.x] = s;
    __syncthreads();
    for (int off = 128; off > 0; off >>= 1) {
        if (threadIdx.x < off) sdata[threadIdx.x] += sdata[threadIdx.x + off];
        __syncthreads();
    }
    if (threadIdx.x == 0) bsum[blockIdx.x] = sdata[0];
}

__global__ void k_scan_top(int* __restrict__ bsum, int* __restrict__ offs) {
    int lane = threadIdx.x; // 0..63, one wave
    int v = (lane < NSB) ? bsum[lane] : 0;
    int x = v;
    for (int off = 1; off < 64; off <<= 1) {
        int t = __shfl_up(x, off);
        if (lane >= off) x += t;
    }
    bsum[lane] = x - v;
    if (lane == 63) offs[N_NODES] = x;
}

__global__ void k_scan_write(const int* __restrict__ deg, const int* __restrict__ bsum,
                             int* __restrict__ offs) {
    __shared__ int sdata[256];
    const int PT = SCAN_CHUNK / 256; // 8
    int base = blockIdx.x * SCAN_CHUNK;
    int tb = base + threadIdx.x * PT;
    int loc[PT];
    int s = 0;
    for (int m = 0; m < PT; ++m) {
        int i = tb + m;
        int d = (i < N_NODES) ? deg[i] : 0;
        loc[m] = s;
        s += d;
    }
    sdata[threadIdx.x] = s;
    __syncthreads();
    for (int off = 1; off < 256; off <<= 1) {
        int t = (threadIdx.x >= off) ? sdata[threadIdx.x - off] : 0;
        __syncthreads();
        sdata[threadIdx.x] += t;
        __syncthreads();
    }
    int texcl = sdata[threadIdx.x] - s + bsum[blockIdx.x];
    for (int m = 0; m < PT; ++m) {
        int i = tb + m;
        if (i < N_NODES) offs[i] = texcl + loc[m];
    }
}

// ---------------- two-pass binned CSR build ----------------

// bcur[b] = start of bucket b's CSR span (rebuilt every launch from offs)
__global__ void k_binit(const int* __restrict__ offs, int* __restrict__ bcur) {
    int b = threadIdx.x;
    if (b < NBUCK) {
        int g = b << BSH;
        bcur[b] = offs[(g < N_NODES) ? g : N_NODES];
    }
}

// Pass A: tile 2048 edges -> LDS histogram over buckets -> reserve per-bucket
// chunks (1 global atomic per block,bucket) -> write packed (src<<9)|localT
// into bucket-partitioned staging in ~10-edge chunks (line-friendly writes).
__global__ __launch_bounds__(256) void k_bin(const int* __restrict__ ei,
                                             int* __restrict__ bcur,
                                             unsigned* __restrict__ staging) {
    __shared__ int cnt[256];
    __shared__ int base[256];
    const int tid = threadIdx.x;
    cnt[tid] = 0;
    __syncthreads();
    const int e0 = blockIdx.x * BIN_TILE;
    unsigned pk[BIN_EPT];
    int bk[BIN_EPT];
#pragma unroll
    for (int r = 0; r < BIN_EPT; ++r) {
        int e = e0 + r * 256 + tid;
        if (e < N_EDGES) {
            int t = __builtin_nontemporal_load(ei + N_EDGES + e);
            int s = __builtin_nontemporal_load(ei + e);
            bk[r] = t >> BSH;
            pk[r] = ((unsigned)s << BSH) | (unsigned)(t & (BTGT - 1));
            atomicAdd(&cnt[bk[r]], 1);
        } else {
            bk[r] = -1;
        }
    }
    __syncthreads();
    if (tid < NBUCK) {
        int c = cnt[tid];
        base[tid] = (c > 0) ? atomicAdd(&bcur[tid], c) : 0;
    }
    __syncthreads();
#pragma unroll
    for (int r = 0; r < BIN_EPT; ++r) {
        if (bk[r] >= 0) {
            int g = atomicAdd(&base[bk[r]], 1);
            staging[g] = pk[r];
        }
    }
}

// Pass B: one block per bucket. Per-target cursors in LDS (from offs); read
// the bucket's staging segment coalesced; scatter within the bucket's ~32KB
// contiguous CSR window -> full lines, no global atomics.
__global__ __launch_bounds__(256) void k_scatter(const unsigned* __restrict__ staging,
                                                 const int* __restrict__ offs,
                                                 int* __restrict__ csr_row) {
    __shared__ int curs[BTGT];
    const int b = blockIdx.x;
    const int tid = threadIdx.x;
    const int g0 = b << BSH;
#pragma unroll
    for (int i = tid; i < BTGT; i += 256) {
        int g = g0 + i;
        curs[i] = offs[(g < N_NODES) ? g : N_NODES];
    }
    const int lo = offs[(g0 < N_NODES) ? g0 : N_NODES];
    const int g1 = g0 + BTGT;
    const int hi = offs[(g1 < N_NODES) ? g1 : N_NODES];
    __syncthreads();
    for (int j = lo + tid; j < hi; j += 256) {
        unsigned p = staging[j];
        int lt = p & (BTGT - 1);
        int src = (int)(p >> BSH);
        int pos = atomicAdd(&curs[lt], 1);
        csr_row[pos] = src;
    }
}

// ---------------- dinv-scaled GEMM -> bf16, 4x8 per-thread tile ----------------
// Block tile: BN nodes x OUTTOT outs (layer1 64x128, layer2 128x64).
// Per k-step: 4 broadcast b32 + 2 b128 LDS reads feed 32 FMAs -> VALU-bound.

template <int BN, int OUTTOT>
__global__ __launch_bounds__(256) void k_gemm2(const float* __restrict__ X,
                                               const float* __restrict__ W,
                                               const float* __restrict__ dinv,
                                               unsigned short* __restrict__ outb) {
    constexpr int OG = OUTTOT / 8;   // out groups (16 or 8)
    constexpr int NG = 256 / OG;     // node groups (16 or 32); NG*4 == BN
    static_assert(NG * 4 == BN, "tile mismatch");
    constexpr int XV = BN / 16;      // float4 xs loads per thread per half
    constexpr int WQ = OUTTOT / 4;   // float4 per wsh row
    constexpr int WV = OUTTOT / 16;  // float4 wsh loads per thread per half

    __shared__ float xs[BN][68];
    __shared__ float wsh[64][OUTTOT];
    const int tid = threadIdx.x;
    const int oq = tid % OG;
    const int nq = tid / OG;
    const int n0 = blockIdx.x * BN;
    float acc[4][8] = {};

    for (int kh = 0; kh < 2; ++kh) {
#pragma unroll
        for (int m = 0; m < XV; ++m) {
            int q = tid + 256 * m;
            int row = q >> 4, kq = q & 15;
            int nn = n0 + row;
            float4 v = make_float4(0.f, 0.f, 0.f, 0.f);
            if (nn < N_NODES)
                v = *reinterpret_cast<const float4*>(X + (size_t)nn * 128 + kh * 64 + kq * 4);
            *reinterpret_cast<float4*>(&xs[row][kq * 4]) = v;
        }
#pragma unroll
        for (int m = 0; m < WV; ++m) {
            int q = tid + 256 * m;
            int row = q / WQ, fq = q % WQ;
            float4 v = *reinterpret_cast<const float4*>(W + (size_t)(kh * 64 + row) * OUTTOT +
                                                        fq * 4);
            *reinterpret_cast<float4*>(&wsh[row][fq * 4]) = v;
        }
        __syncthreads();
#pragma unroll 8
        for (int k = 0; k < 64; ++k) {
            const float4 w0 = *reinterpret_cast<const float4*>(&wsh[k][oq * 8]);
            const float4 w1 = *reinterpret_cast<const float4*>(&wsh[k][oq * 8 + 4]);
#pragma unroll
            for (int j = 0; j < 4; ++j) {
                float xv = xs[nq + NG * j][k];
                acc[j][0] += xv * w0.x;
                acc[j][1] += xv * w0.y;
                acc[j][2] += xv * w0.z;
                acc[j][3] += xv * w0.w;
                acc[j][4] += xv * w1.x;
                acc[j][5] += xv * w1.y;
                acc[j][6] += xv * w1.z;
                acc[j][7] += xv * w1.w;
            }
        }
        __syncthreads();
    }
#pragma unroll
    for (int j = 0; j < 4; ++j) {
        int nn = n0 + nq + NG * j;
        if (nn < N_NODES) {
            float s = dinv[nn];
            uint4 pkv;
            pkv.x = pack_bf2(acc[j][0] * s, acc[j][1] * s);
            pkv.y = pack_bf2(acc[j][2] * s, acc[j][3] * s);
            pkv.z = pack_bf2(acc[j][4] * s, acc[j][5] * s);
            pkv.w = pack_bf2(acc[j][6] * s, acc[j][7] * s);
            *reinterpret_cast<uint4*>(outb + (size_t)nn * OUTTOT + oq * 8) = pkv;
        }
    }
}

// ---------------- CSR aggregation over bf16 rows, latency-optimized ----------------

template <int OC, int U, bool RELU>
__global__ __launch_bounds__(256) void k_aggv(const uint4* __restrict__ hs,
                                              const int* __restrict__ csr_row,
                                              const int* __restrict__ offs,
                                              const float* __restrict__ dinv,
                                              const float* __restrict__ bias,
                                              float* __restrict__ out) {
    constexpr int LPR = (OC * 2) / 16;   // 16 (OC=128) or 8 (OC=64)
    constexpr int SLOTS = 64 / LPR;      // 4 or 8
    const int lane = threadIdx.x & 63;
    const int sub = lane / LPR;
    const int q = lane % LPR;
    const int wid = (blockIdx.x * 4) + (threadIdx.x >> 6);
    const int nwaves = gridDim.x * 4;

    for (int t = wid; t < N_NODES; t += nwaves) {
        const int s = offs[t], e2 = offs[t + 1];
        float acc[8] = {0.f, 0.f, 0.f, 0.f, 0.f, 0.f, 0.f, 0.f};
        for (int j = s; j < e2; j += U * SLOTS) {
            int rr[U];
#pragma unroll
            for (int u = 0; u < U; ++u) {
                int jj = j + u * SLOTS + sub;
                rr[u] = (jj < e2) ? __builtin_nontemporal_load(csr_row + jj) : -1;
            }
            uint4 vv[U];
#pragma unroll
            for (int u = 0; u < U; ++u) {
                vv[u] = make_uint4(0u, 0u, 0u, 0u);
                if (rr[u] >= 0) vv[u] = hs[(size_t)rr[u] * LPR + q];
            }
#pragma unroll
            for (int u = 0; u < U; ++u) {
                acc[0] += blo(vv[u].x);
                acc[1] += bhi(vv[u].x);
                acc[2] += blo(vv[u].y);
                acc[3] += bhi(vv[u].y);
                acc[4] += blo(vv[u].z);
                acc[5] += bhi(vv[u].z);
                acc[6] += blo(vv[u].w);
                acc[7] += bhi(vv[u].w);
            }
        }
#pragma unroll
        for (int off = 32; off >= LPR; off >>= 1) {
#pragma unroll
            for (int i = 0; i < 8; ++i) acc[i] += __shfl_xor(acc[i], off);
        }
        if (lane < LPR) {
            const float dt = dinv[t];
            const float4 b0 = *reinterpret_cast<const float4*>(bias + lane * 8);
            const float4 b1 = *reinterpret_cast<const float4*>(bias + lane * 8 + 4);
            float4 r0, r1;
            r0.x = acc[0] * dt + b0.x;
            r0.y = acc[1] * dt + b0.y;
            r0.z = acc[2] * dt + b0.z;
            r0.w = acc[3] * dt + b0.w;
            r1.x = acc[4] * dt + b1.x;
            r1.y = acc[5] * dt + b1.y;
            r1.z = acc[6] * dt + b1.z;
            r1.w = acc[7] * dt + b1.w;
            if (RELU) {
                r0.x = fmaxf(r0.x, 0.f); r0.y = fmaxf(r0.y, 0.f);
                r0.z = fmaxf(r0.z, 0.f); r0.w = fmaxf(r0.w, 0.f);
                r1.x = fmaxf(r1.x, 0.f); r1.y = fmaxf(r1.y, 0.f);
                r1.z = fmaxf(r1.z, 0.f); r1.w = fmaxf(r1.w, 0.f);
            }
            float* po = out + (size_t)t * OC + lane * 8;
            *reinterpret_cast<float4*>(po) = r0;
            *reinterpret_cast<float4*>(po + 4) = r1;
        }
    }
}

// ---------------- launch ----------------

extern "C" void kernel_launch(void* const* d_in, const int* in_sizes, int n_in,
                              void* d_out, int out_size, void* d_ws, size_t ws_size,
                              hipStream_t stream) {
    const float* x  = (const float*)d_in[0];
    const int*   ei = (const int*)d_in[1];
    const float* W1 = (const float*)d_in[2];
    const float* b1 = (const float*)d_in[3];
    const float* W2 = (const float*)d_in[4];
    const float* b2 = (const float*)d_in[5];
    float* out = (float*)d_out;

    char* w = (char*)d_ws;
    auto alloc = [&](size_t bytes) {
        void* p = (void*)w;
        w += (bytes + 255) & ~(size_t)255;
        return p;
    };
    int*   deg     = (int*)alloc((size_t)N_NODES * 4);
    float* dinv    = (float*)alloc((size_t)N_NODES * 4);
    int*   offs    = (int*)alloc((size_t)(N_NODES + 1) * 4);
    int*   bcur    = (int*)alloc((size_t)NBUCK * 4);
    int*   bsum    = (int*)alloc(64 * 4);
    int*   hist    = (int*)alloc((size_t)NPASS * N_NODES * 4);
    unsigned* staging = (unsigned*)alloc((size_t)N_EDGES * 4);
    int*   csr_row = (int*)alloc((size_t)N_EDGES * 4);
    unsigned short* hs1 = (unsigned short*)alloc((size_t)N_NODES * HIDC * 2); // bf16
    float* h       = (float*)alloc((size_t)N_NODES * HIDC * 4);
    unsigned short* hs2 = hs1; // bf16, reuse (hs1 dead after layer-1 agg)

    // norm + offsets
    k_zero<<<(NPASS * N_NODES + 255) / 256, 256, 0, stream>>>(hist, NPASS * N_NODES);
    k_count_priv<<<3072, 256, 0, stream>>>(ei, hist);
    k_degsum<<<(N_NODES + 255) / 256, 256, 0, stream>>>(hist, deg, dinv);
    k_scan_part<<<NSB, 256, 0, stream>>>(deg, bsum);
    k_scan_top<<<1, 64, 0, stream>>>(bsum, offs);
    k_scan_write<<<NSB, 256, 0, stream>>>(deg, bsum, offs);

    // two-pass binned CSR build
    k_binit<<<1, 256, 0, stream>>>(offs, bcur);
    k_bin<<<NBINBLK, 256, 0, stream>>>(ei, bcur, staging);
    k_scatter<<<NBUCK, 256, 0, stream>>>(staging, offs, csr_row);

    // layer 1: 64 nodes x 128 outs per block
    k_gemm2<64, HIDC><<<(N_NODES + 63) / 64, 256, 0, stream>>>(x, W1, dinv, hs1);
    k_aggv<HIDC, 4, true><<<2048, 256, 0, stream>>>((const uint4*)hs1, csr_row, offs, dinv, b1, h);

    // layer 2: 128 nodes x 64 outs per block
    k_gemm2<128, OUTC><<<(N_NODES + 127) / 128, 256, 0, stream>>>(h, W2, dinv, hs2);
    k_aggv<OUTC, 2, false><<<2048, 256, 0, stream>>>((const uint4*)hs2, csr_row, offs, dinv, b2, out);
}

// Round 8
// 402.437 us; speedup vs baseline: 1.2288x; 1.0461x over previous
//
#include <hip/hip_runtime.h>

#define N_NODES 100000
#define N_EDGES 1600000
#define INC 128
#define HIDC 128
#define OUTC 64

constexpr int SCAN_CHUNK = 2048;
constexpr int NSB = (N_NODES + SCAN_CHUNK - 1) / SCAN_CHUNK; // 49 blocks
constexpr int NPASS = 8;                                      // one per XCD

// Binned scatter geometry: bucket = target >> 9 (512 targets/bucket)
constexpr int BSH = 9;
constexpr int BTGT = 1 << BSH;                                // 512
constexpr int NBUCK = (N_NODES + BTGT - 1) / BTGT;            // 196
constexpr int BIN_TILE = 2048;
constexpr int BIN_EPT = BIN_TILE / 256;                       // 8
constexpr int NBINBLK = (N_EDGES + BIN_TILE - 1) / BIN_TILE;  // 782

// ---------------- bf16 helpers ----------------

__device__ __forceinline__ float blo(unsigned u) { return __uint_as_float(u << 16); }
__device__ __forceinline__ float bhi(unsigned u) { return __uint_as_float(u & 0xFFFF0000u); }
__device__ __forceinline__ unsigned pack_bf2(float a, float b) {
    unsigned ua = __float_as_uint(a);
    ua = (ua + 0x7FFFu + ((ua >> 16) & 1u)) >> 16;
    unsigned ub = __float_as_uint(b);
    ub = (ub + 0x7FFFu + ((ub >> 16) & 1u)) >> 16;
    return ua | (ub << 16);
}

// ---------------- small utility kernels ----------------

__global__ void k_zero(int* __restrict__ p, int n) {
    int i = blockIdx.x * 256 + threadIdx.x;
    if (i < n) p[i] = 0;
}

// Per-XCD private degree histograms over DISJOINT edge ranges; nt stream read.
__global__ void k_count_priv(const int* __restrict__ ei, int* __restrict__ hist) {
    const int pass = blockIdx.x & 7;
    const int bid = blockIdx.x >> 3;
    const int nb = gridDim.x >> 3;
    int* hp = hist + (size_t)pass * N_NODES;
    const int e0 = (int)((long long)pass * N_EDGES / NPASS);
    const int e1 = (int)((long long)(pass + 1) * N_EDGES / NPASS);
    for (int e = e0 + bid * 256 + threadIdx.x; e < e1; e += nb * 256) {
        int t = __builtin_nontemporal_load(ei + N_EDGES + e);
        atomicAdd(&hp[t], 1);
    }
}

// deg = column-sum of the 8 histograms; dinv = rsqrt(deg)
__global__ void k_degsum(const int* __restrict__ hist, int* __restrict__ deg,
                         float* __restrict__ dinv) {
    int i = blockIdx.x * 256 + threadIdx.x;
    if (i < N_NODES) {
        int d = 0;
#pragma unroll
        for (int p = 0; p < NPASS; ++p) d += hist[(size_t)p * N_NODES + i];
        deg[i] = d;
        dinv[i] = (d > 0) ? rsqrtf((float)d) : 0.f;
    }
}

// ---------------- hierarchical exclusive scan of deg -> offs ----------------

__global__ void k_scan_part(const int* __restrict__ deg, int* __restrict__ bsum) {
    __shared__ int sdata[256];
    int base = blockIdx.x * SCAN_CHUNK;
    int s = 0;
    for (int m = 0; m < SCAN_CHUNK / 256; ++m) {
        int i = base + m * 256 + threadIdx.x;
        s += (i < N_NODES) ? deg[i] : 0;
    }
    sdata[threadIdx.x] = s;
    __syncthreads();
    for (int off = 128; off > 0; off >>= 1) {
        if (threadIdx.x < off) sdata[threadIdx.x] += sdata[threadIdx.x + off];
        __syncthreads();
    }
    if (threadIdx.x == 0) bsum[blockIdx.x] = sdata[0];
}

__global__ void k_scan_top(int* __restrict__ bsum, int* __restrict__ offs) {
    int lane = threadIdx.x; // 0..63, one wave
    int v = (lane < NSB) ? bsum[lane] : 0;
    int x = v;
    for (int off = 1; off < 64; off <<= 1) {
        int t = __shfl_up(x, off);
        if (lane >= off) x += t;
    }
    bsum[lane] = x - v;
    if (lane == 63) offs[N_NODES] = x;
}

__global__ void k_scan_write(const int* __restrict__ deg, const int* __restrict__ bsum,
                             int* __restrict__ offs) {
    __shared__ int sdata[256];
    const int PT = SCAN_CHUNK / 256; // 8
    int base = blockIdx.x * SCAN_CHUNK;
    int tb = base + threadIdx.x * PT;
    int loc[PT];
    int s = 0;
    for (int m = 0; m < PT; ++m) {
        int i = tb + m;
        int d = (i < N_NODES) ? deg[i] : 0;
        loc[m] = s;
        s += d;
    }
    sdata[threadIdx.x] = s;
    __syncthreads();
    for (int off = 1; off < 256; off <<= 1) {
        int t = (threadIdx.x >= off) ? sdata[threadIdx.x - off] : 0;
        __syncthreads();
        sdata[threadIdx.x] += t;
        __syncthreads();
    }
    int texcl = sdata[threadIdx.x] - s + bsum[blockIdx.x];
    for (int m = 0; m < PT; ++m) {
        int i = tb + m;
        if (i < N_NODES) offs[i] = texcl + loc[m];
    }
}

// ---------------- two-pass binned CSR build ----------------

__global__ void k_binit(const int* __restrict__ offs, int* __restrict__ bcur) {
    int b = threadIdx.x;
    if (b < NBUCK) {
        int g = b << BSH;
        bcur[b] = offs[(g < N_NODES) ? g : N_NODES];
    }
}

// Pass A: tile 2048 edges -> LDS histogram over buckets -> reserve per-bucket
// chunks (1 global atomic per block,bucket) -> write packed (src<<9)|localT
// into bucket-partitioned staging in ~10-edge chunks (line-friendly writes).
__global__ __launch_bounds__(256) void k_bin(const int* __restrict__ ei,
                                             int* __restrict__ bcur,
                                             unsigned* __restrict__ staging) {
    __shared__ int cnt[256];
    __shared__ int base[256];
    const int tid = threadIdx.x;
    cnt[tid] = 0;
    __syncthreads();
    const int e0 = blockIdx.x * BIN_TILE;
    unsigned pk[BIN_EPT];
    int bk[BIN_EPT];
#pragma unroll
    for (int r = 0; r < BIN_EPT; ++r) {
        int e = e0 + r * 256 + tid;
        if (e < N_EDGES) {
            int t = __builtin_nontemporal_load(ei + N_EDGES + e);
            int s = __builtin_nontemporal_load(ei + e);
            bk[r] = t >> BSH;
            pk[r] = ((unsigned)s << BSH) | (unsigned)(t & (BTGT - 1));
            atomicAdd(&cnt[bk[r]], 1);
        } else {
            bk[r] = -1;
        }
    }
    __syncthreads();
    if (tid < NBUCK) {
        int c = cnt[tid];
        base[tid] = (c > 0) ? atomicAdd(&bcur[tid], c) : 0;
    }
    __syncthreads();
#pragma unroll
    for (int r = 0; r < BIN_EPT; ++r) {
        if (bk[r] >= 0) {
            int g = atomicAdd(&base[bk[r]], 1);
            staging[g] = pk[r];
        }
    }
}

// Pass B: one block per bucket; per-target cursors in LDS; coalesced staging
// read; scatter within the bucket's ~32KB contiguous CSR window.
__global__ __launch_bounds__(256) void k_scatter(const unsigned* __restrict__ staging,
                                                 const int* __restrict__ offs,
                                                 int* __restrict__ csr_row) {
    __shared__ int curs[BTGT];
    const int b = blockIdx.x;
    const int tid = threadIdx.x;
    const int g0 = b << BSH;
#pragma unroll
    for (int i = tid; i < BTGT; i += 256) {
        int g = g0 + i;
        curs[i] = offs[(g < N_NODES) ? g : N_NODES];
    }
    const int lo = offs[(g0 < N_NODES) ? g0 : N_NODES];
    const int g1 = g0 + BTGT;
    const int hi = offs[(g1 < N_NODES) ? g1 : N_NODES];
    __syncthreads();
    for (int j = lo + tid; j < hi; j += 256) {
        unsigned p = staging[j];
        int lt = p & (BTGT - 1);
        int src = (int)(p >> BSH);
        int pos = atomicAdd(&curs[lt], 1);
        csr_row[pos] = src;
    }
}

// ---------------- dinv-scaled GEMM -> bf16, conflict-free 4x8 tile ----------------
// W staged de-interleaved: wa[k][g*4+i]=W[k][g*8+i], wb[k][g*4+i]=W[k][g*8+4+i]
// -> the two per-k b128 reads span HW dwords => 2-way (L1) / 0-way (L2), free.
// K-chunk 32 -> ~26KB LDS -> 6 blocks/CU.

template <int BN, int OUTTOT>
__global__ __launch_bounds__(256) void k_gemm3(const float* __restrict__ X,
                                               const float* __restrict__ W,
                                               const float* __restrict__ dinv,
                                               unsigned short* __restrict__ outb) {
    constexpr int OG = OUTTOT / 8;   // out groups: 16 (L1) / 8 (L2)
    constexpr int NG = 256 / OG;     // node groups: 16 / 32; NG*4 == BN
    static_assert(NG * 4 == BN, "tile mismatch");
    constexpr int KC = 32;           // k-chunk
    constexpr int HW = OUTTOT / 2;   // half-width floats (64 / 32)
    constexpr int XITER = (BN * KC) / 1024;     // 2 / 4
    constexpr int WITER = (KC * OUTTOT) / 1024; // 4 / 2

    __shared__ float xs[BN][KC + 4];
    __shared__ float wa[KC][HW];
    __shared__ float wb[KC][HW];

    const int tid = threadIdx.x;
    const int oq = tid % OG;
    const int nq = tid / OG;
    const int n0 = blockIdx.x * BN;
    float acc[4][8] = {};

    for (int kc = 0; kc < 128; kc += KC) {
#pragma unroll
        for (int m = 0; m < XITER; ++m) {
            int q = tid + 256 * m;
            int row = q / (KC / 4);
            int kq = q % (KC / 4);
            int nn = n0 + row;
            float4 v = make_float4(0.f, 0.f, 0.f, 0.f);
            if (nn < N_NODES)
                v = *reinterpret_cast<const float4*>(X + (size_t)nn * 128 + kc + kq * 4);
            *reinterpret_cast<float4*>(&xs[row][kq * 4]) = v;
        }
#pragma unroll
        for (int m = 0; m < WITER; ++m) {
            int q = tid + 256 * m;
            int row = q / (OUTTOT / 4);
            int fq = q % (OUTTOT / 4);
            float4 v = *reinterpret_cast<const float4*>(W + (size_t)(kc + row) * OUTTOT + fq * 4);
            float* dst = (fq & 1) ? &wb[row][(fq >> 1) * 4] : &wa[row][(fq >> 1) * 4];
            *reinterpret_cast<float4*>(dst) = v;
        }
        __syncthreads();
#pragma unroll 8
        for (int k = 0; k < KC; ++k) {
            const float4 w0 = *reinterpret_cast<const float4*>(&wa[k][oq * 4]);
            const float4 w1 = *reinterpret_cast<const float4*>(&wb[k][oq * 4]);
#pragma unroll
            for (int j = 0; j < 4; ++j) {
                float xv = xs[nq + NG * j][k];
                acc[j][0] += xv * w0.x;
                acc[j][1] += xv * w0.y;
                acc[j][2] += xv * w0.z;
                acc[j][3] += xv * w0.w;
                acc[j][4] += xv * w1.x;
                acc[j][5] += xv * w1.y;
                acc[j][6] += xv * w1.z;
                acc[j][7] += xv * w1.w;
            }
        }
        __syncthreads();
    }
#pragma unroll
    for (int j = 0; j < 4; ++j) {
        int nn = n0 + nq + NG * j;
        if (nn < N_NODES) {
            float s = dinv[nn];
            uint4 pkv;
            pkv.x = pack_bf2(acc[j][0] * s, acc[j][1] * s);
            pkv.y = pack_bf2(acc[j][2] * s, acc[j][3] * s);
            pkv.z = pack_bf2(acc[j][4] * s, acc[j][5] * s);
            pkv.w = pack_bf2(acc[j][6] * s, acc[j][7] * s);
            *reinterpret_cast<uint4*>(outb + (size_t)nn * OUTTOT + oq * 8) = pkv;
        }
    }
}

// ---------------- CSR aggregation over bf16 rows, latency-optimized ----------------

template <int OC, int U, bool RELU>
__global__ __launch_bounds__(256) void k_aggv(const uint4* __restrict__ hs,
                                              const int* __restrict__ csr_row,
                                              const int* __restrict__ offs,
                                              const float* __restrict__ dinv,
                                              const float* __restrict__ bias,
                                              float* __restrict__ out) {
    constexpr int LPR = (OC * 2) / 16;   // 16 (OC=128) or 8 (OC=64)
    constexpr int SLOTS = 64 / LPR;      // 4 or 8
    const int lane = threadIdx.x & 63;
    const int sub = lane / LPR;
    const int q = lane % LPR;
    const int wid = (blockIdx.x * 4) + (threadIdx.x >> 6);
    const int nwaves = gridDim.x * 4;

    for (int t = wid; t < N_NODES; t += nwaves) {
        const int s = offs[t], e2 = offs[t + 1];
        float acc[8] = {0.f, 0.f, 0.f, 0.f, 0.f, 0.f, 0.f, 0.f};
        for (int j = s; j < e2; j += U * SLOTS) {
            int rr[U];
#pragma unroll
            for (int u = 0; u < U; ++u) {
                int jj = j + u * SLOTS + sub;
                rr[u] = (jj < e2) ? __builtin_nontemporal_load(csr_row + jj) : -1;
            }
            uint4 vv[U];
#pragma unroll
            for (int u = 0; u < U; ++u) {
                vv[u] = make_uint4(0u, 0u, 0u, 0u);
                if (rr[u] >= 0) vv[u] = hs[(size_t)rr[u] * LPR + q];
            }
#pragma unroll
            for (int u = 0; u < U; ++u) {
                acc[0] += blo(vv[u].x);
                acc[1] += bhi(vv[u].x);
                acc[2] += blo(vv[u].y);
                acc[3] += bhi(vv[u].y);
                acc[4] += blo(vv[u].z);
                acc[5] += bhi(vv[u].z);
                acc[6] += blo(vv[u].w);
                acc[7] += bhi(vv[u].w);
            }
        }
#pragma unroll
        for (int off = 32; off >= LPR; off >>= 1) {
#pragma unroll
            for (int i = 0; i < 8; ++i) acc[i] += __shfl_xor(acc[i], off);
        }
        if (lane < LPR) {
            const float dt = dinv[t];
            const float4 b0 = *reinterpret_cast<const float4*>(bias + lane * 8);
            const float4 b1 = *reinterpret_cast<const float4*>(bias + lane * 8 + 4);
            float4 r0, r1;
            r0.x = acc[0] * dt + b0.x;
            r0.y = acc[1] * dt + b0.y;
            r0.z = acc[2] * dt + b0.z;
            r0.w = acc[3] * dt + b0.w;
            r1.x = acc[4] * dt + b1.x;
            r1.y = acc[5] * dt + b1.y;
            r1.z = acc[6] * dt + b1.z;
            r1.w = acc[7] * dt + b1.w;
            if (RELU) {
                r0.x = fmaxf(r0.x, 0.f); r0.y = fmaxf(r0.y, 0.f);
                r0.z = fmaxf(r0.z, 0.f); r0.w = fmaxf(r0.w, 0.f);
                r1.x = fmaxf(r1.x, 0.f); r1.y = fmaxf(r1.y, 0.f);
                r1.z = fmaxf(r1.z, 0.f); r1.w = fmaxf(r1.w, 0.f);
            }
            float* po = out + (size_t)t * OC + lane * 8;
            *reinterpret_cast<float4*>(po) = r0;
            *reinterpret_cast<float4*>(po + 4) = r1;
        }
    }
}

// ---------------- launch ----------------

extern "C" void kernel_launch(void* const* d_in, const int* in_sizes, int n_in,
                              void* d_out, int out_size, void* d_ws, size_t ws_size,
                              hipStream_t stream) {
    const float* x  = (const float*)d_in[0];
    const int*   ei = (const int*)d_in[1];
    const float* W1 = (const float*)d_in[2];
    const float* b1 = (const float*)d_in[3];
    const float* W2 = (const float*)d_in[4];
    const float* b2 = (const float*)d_in[5];
    float* out = (float*)d_out;

    char* w = (char*)d_ws;
    auto alloc = [&](size_t bytes) {
        void* p = (void*)w;
        w += (bytes + 255) & ~(size_t)255;
        return p;
    };
    int*   deg     = (int*)alloc((size_t)N_NODES * 4);
    float* dinv    = (float*)alloc((size_t)N_NODES * 4);
    int*   offs    = (int*)alloc((size_t)(N_NODES + 1) * 4);
    int*   bcur    = (int*)alloc((size_t)NBUCK * 4);
    int*   bsum    = (int*)alloc(64 * 4);
    int*   hist    = (int*)alloc((size_t)NPASS * N_NODES * 4);
    unsigned* staging = (unsigned*)alloc((size_t)N_EDGES * 4);
    int*   csr_row = (int*)alloc((size_t)N_EDGES * 4);
    unsigned short* hs1 = (unsigned short*)alloc((size_t)N_NODES * HIDC * 2); // bf16
    float* h       = (float*)alloc((size_t)N_NODES * HIDC * 4);
    unsigned short* hs2 = hs1; // bf16, reuse (hs1 dead after layer-1 agg)

    // norm + offsets
    k_zero<<<(NPASS * N_NODES + 255) / 256, 256, 0, stream>>>(hist, NPASS * N_NODES);
    k_count_priv<<<3072, 256, 0, stream>>>(ei, hist);
    k_degsum<<<(N_NODES + 255) / 256, 256, 0, stream>>>(hist, deg, dinv);
    k_scan_part<<<NSB, 256, 0, stream>>>(deg, bsum);
    k_scan_top<<<1, 64, 0, stream>>>(bsum, offs);
    k_scan_write<<<NSB, 256, 0, stream>>>(deg, bsum, offs);

    // two-pass binned CSR build
    k_binit<<<1, 256, 0, stream>>>(offs, bcur);
    k_bin<<<NBINBLK, 256, 0, stream>>>(ei, bcur, staging);
    k_scatter<<<NBUCK, 256, 0, stream>>>(staging, offs, csr_row);

    // layer 1: 64 nodes x 128 outs per block
    k_gemm3<64, HIDC><<<(N_NODES + 63) / 64, 256, 0, stream>>>(x, W1, dinv, hs1);
    k_aggv<HIDC, 4, true><<<2048, 256, 0, stream>>>((const uint4*)hs1, csr_row, offs, dinv, b1, h);

    // layer 2: 128 nodes x 64 outs per block
    k_gemm3<128, OUTC><<<(N_NODES + 127) / 128, 256, 0, stream>>>(h, W2, dinv, hs2);
    k_aggv<OUTC, 2, false><<<2048, 256, 0, stream>>>((const uint4*)hs2, csr_row, offs, dinv, b2, out);
}

// Round 10
// 335.774 us; speedup vs baseline: 1.4728x; 1.1985x over previous
//
#include <hip/hip_runtime.h>

#define N_NODES 100000
#define N_EDGES 1600000
#define INC 128
#define HIDC 128
#define OUTC 64

// Binned scatter geometry: bucket = target >> 9 (512 targets/bucket)
constexpr int BSH = 9;
constexpr int BTGT = 1 << BSH;                                // 512
constexpr int NBUCK = (N_NODES + BTGT - 1) / BTGT;            // 196
constexpr int BCAP = 10240;                                   // fixed bucket capacity (mean 8163, sd~90)
constexpr int BIN_TILE = 2048;
constexpr int BIN_EPT = BIN_TILE / 256;                       // 8
constexpr int NBINBLK = (N_EDGES + BIN_TILE - 1) / BIN_TILE;  // 782

// ---------------- bf16 helpers ----------------

__device__ __forceinline__ float blo(unsigned u) { return __uint_as_float(u << 16); }
__device__ __forceinline__ float bhi(unsigned u) { return __uint_as_float(u & 0xFFFF0000u); }
__device__ __forceinline__ unsigned pack_bf2(float a, float b) {
    unsigned ua = __float_as_uint(a);
    ua = (ua + 0x7FFFu + ((ua >> 16) & 1u)) >> 16;
    unsigned ub = __float_as_uint(b);
    ub = (ub + 0x7FFFu + ((ub >> 16) & 1u)) >> 16;
    return ua | (ub << 16);
}

// ---------------- fixed-capacity binned CSR build (no pre-count) ----------------

__global__ void k_binit(int* __restrict__ bcur) {
    int b = threadIdx.x;
    if (b < NBUCK) bcur[b] = b * BCAP;
}

// Pass A: tile 2048 edges -> LDS histogram over buckets -> reserve per-bucket
// chunks (1 global atomic per block,bucket) -> write packed (src<<9)|localT
// into fixed-capacity bucket regions in ~10-edge chunks (line-friendly).
__global__ __launch_bounds__(256) void k_bin(const int* __restrict__ ei,
                                             int* __restrict__ bcur,
                                             unsigned* __restrict__ staging) {
    __shared__ int cnt[256];
    __shared__ int base[256];
    const int tid = threadIdx.x;
    cnt[tid] = 0;
    __syncthreads();
    const int e0 = blockIdx.x * BIN_TILE;
    unsigned pk[BIN_EPT];
    int bk[BIN_EPT];
#pragma unroll
    for (int r = 0; r < BIN_EPT; ++r) {
        int e = e0 + r * 256 + tid;
        if (e < N_EDGES) {
            int t = __builtin_nontemporal_load(ei + N_EDGES + e);
            int s = __builtin_nontemporal_load(ei + e);
            bk[r] = t >> BSH;
            pk[r] = ((unsigned)s << BSH) | (unsigned)(t & (BTGT - 1));
            atomicAdd(&cnt[bk[r]], 1);
        } else {
            bk[r] = -1;
        }
    }
    __syncthreads();
    if (tid < NBUCK) {
        int c = cnt[tid];
        base[tid] = (c > 0) ? atomicAdd(&bcur[tid], c) : 0;
    }
    __syncthreads();
#pragma unroll
    for (int r = 0; r < BIN_EPT; ++r) {
        if (bk[r] >= 0) {
            int g = atomicAdd(&base[bk[r]], 1);
            staging[g] = pk[r];
        }
    }
}

// One block: scan the 196 bucket totals -> bucket CSR bases; offs[N] = E.
__global__ void k_bucket_scan(const int* __restrict__ bcur, int* __restrict__ bbase,
                              int* __restrict__ offs) {
    __shared__ int sdata[256];
    const int tid = threadIdx.x;
    int v = (tid < NBUCK) ? (bcur[tid] - tid * BCAP) : 0;
    sdata[tid] = v;
    __syncthreads();
    for (int off = 1; off < 256; off <<= 1) {
        int t = (tid >= off) ? sdata[tid - off] : 0;
        __syncthreads();
        sdata[tid] += t;
        __syncthreads();
    }
    if (tid < NBUCK) bbase[tid] = sdata[tid] - v;
    if (tid == 0) offs[N_NODES] = N_EDGES;
}

// Pass B: one block per bucket. Count per-target in LDS, 512-wide LDS scan ->
// offs + dinv + cursors, then place csr_row within the bucket's contiguous
// ~32KB window (full lines, no global atomics). Replaces the whole
// count/degsum/global-scan pipeline.
__global__ __launch_bounds__(256) void k_scatter2(const unsigned* __restrict__ staging,
                                                  const int* __restrict__ bcur,
                                                  const int* __restrict__ bbase,
                                                  int* __restrict__ offs,
                                                  float* __restrict__ dinv,
                                                  int* __restrict__ csr_row) {
    __shared__ int cnt[BTGT];
    __shared__ int pos[BTGT];
    __shared__ int sdata[256];
    const int b = blockIdx.x;
    const int tid = threadIdx.x;
    const int segb = b * BCAP;
    const int n = bcur[b] - segb;
    const int g0 = b << BSH;
    const int bb = bbase[b];
    cnt[tid] = 0;
    cnt[tid + 256] = 0;
    __syncthreads();
    for (int j = tid; j < n; j += 256) {
        atomicAdd(&cnt[staging[segb + j] & (BTGT - 1)], 1);
    }
    __syncthreads();
    const int c0 = cnt[2 * tid], c1 = cnt[2 * tid + 1];
    const int s = c0 + c1;
    sdata[tid] = s;
    __syncthreads();
    for (int off = 1; off < 256; off <<= 1) {
        int t = (tid >= off) ? sdata[tid - off] : 0;
        __syncthreads();
        sdata[tid] += t;
        __syncthreads();
    }
    const int texcl = sdata[tid] - s;
    const int o0 = bb + texcl;
    const int o1 = o0 + c0;
    const int gg0 = g0 + 2 * tid, gg1 = g0 + 2 * tid + 1;
    if (gg0 < N_NODES) {
        offs[gg0] = o0;
        dinv[gg0] = (c0 > 0) ? rsqrtf((float)c0) : 0.f;
    }
    if (gg1 < N_NODES) {
        offs[gg1] = o1;
        dinv[gg1] = (c1 > 0) ? rsqrtf((float)c1) : 0.f;
    }
    pos[2 * tid] = o0;
    pos[2 * tid + 1] = o1;
    __syncthreads();
    for (int j = tid; j < n; j += 256) {
        unsigned p = staging[segb + j];
        int lt = p & (BTGT - 1);
        int src = (int)(p >> BSH);
        int pp = atomicAdd(&pos[lt], 1);
        csr_row[pp] = src;
    }
}

// ---------------- dinv-scaled GEMM -> bf16, conflict-free 4x8 tile ----------------
// W staged de-interleaved: wa[k][g*4+i]=W[k][g*8+i], wb[k][g*4+i]=W[k][g*8+4+i]
// -> per-k b128 pair spans HW dwords => 2-way (free) / conflict-free.
// K-chunk 32 -> ~26KB LDS -> 6 blocks/CU.

template <int BN, int OUTTOT>
__global__ __launch_bounds__(256) void k_gemm3(const float* __restrict__ X,
                                               const float* __restrict__ W,
                                               const float* __restrict__ dinv,
                                               unsigned short* __restrict__ outb) {
    constexpr int OG = OUTTOT / 8;   // out groups: 16 (L1) / 8 (L2)
    constexpr int NG = 256 / OG;     // node groups: 16 / 32; NG*4 == BN
    static_assert(NG * 4 == BN, "tile mismatch");
    constexpr int KC = 32;           // k-chunk
    constexpr int HW = OUTTOT / 2;   // half-width floats (64 / 32)
    constexpr int XITER = (BN * KC) / 1024;     // 2 / 4
    constexpr int WITER = (KC * OUTTOT) / 1024; // 4 / 2

    __shared__ float xs[BN][KC + 4];
    __shared__ float wa[KC][HW];
    __shared__ float wb[KC][HW];

    const int tid = threadIdx.x;
    const int oq = tid % OG;
    const int nq = tid / OG;
    const int n0 = blockIdx.x * BN;
    float acc[4][8] = {};

    for (int kc = 0; kc < 128; kc += KC) {
#pragma unroll
        for (int m = 0; m < XITER; ++m) {
            int q = tid + 256 * m;
            int row = q / (KC / 4);
            int kq = q % (KC / 4);
            int nn = n0 + row;
            float4 v = make_float4(0.f, 0.f, 0.f, 0.f);
            if (nn < N_NODES)
                v = *reinterpret_cast<const float4*>(X + (size_t)nn * 128 + kc + kq * 4);
            *reinterpret_cast<float4*>(&xs[row][kq * 4]) = v;
        }
#pragma unroll
        for (int m = 0; m < WITER; ++m) {
            int q = tid + 256 * m;
            int row = q / (OUTTOT / 4);
            int fq = q % (OUTTOT / 4);
            float4 v = *reinterpret_cast<const float4*>(W + (size_t)(kc + row) * OUTTOT + fq * 4);
            float* dst = (fq & 1) ? &wb[row][(fq >> 1) * 4] : &wa[row][(fq >> 1) * 4];
            *reinterpret_cast<float4*>(dst) = v;
        }
        __syncthreads();
#pragma unroll 8
        for (int k = 0; k < KC; ++k) {
            const float4 w0 = *reinterpret_cast<const float4*>(&wa[k][oq * 4]);
            const float4 w1 = *reinterpret_cast<const float4*>(&wb[k][oq * 4]);
#pragma unroll
            for (int j = 0; j < 4; ++j) {
                float xv = xs[nq + NG * j][k];
                acc[j][0] += xv * w0.x;
                acc[j][1] += xv * w0.y;
                acc[j][2] += xv * w0.z;
                acc[j][3] += xv * w0.w;
                acc[j][4] += xv * w1.x;
                acc[j][5] += xv * w1.y;
                acc[j][6] += xv * w1.z;
                acc[j][7] += xv * w1.w;
            }
        }
        __syncthreads();
    }
#pragma unroll
    for (int j = 0; j < 4; ++j) {
        int nn = n0 + nq + NG * j;
        if (nn < N_NODES) {
            float s = dinv[nn];
            uint4 pkv;
            pkv.x = pack_bf2(acc[j][0] * s, acc[j][1] * s);
            pkv.y = pack_bf2(acc[j][2] * s, acc[j][3] * s);
            pkv.z = pack_bf2(acc[j][4] * s, acc[j][5] * s);
            pkv.w = pack_bf2(acc[j][6] * s, acc[j][7] * s);
            *reinterpret_cast<uint4*>(outb + (size_t)nn * OUTTOT + oq * 8) = pkv;
        }
    }
}

// ---------------- CSR aggregation, 2-node pipelined ----------------
// One wave per ADJACENT NODE PAIR (coalesced index spans): 2 independent
// gather chains of U each -> 2*U loads in flight per lane (guards on a
// mean-degree-16 node cap a single chain at deg/SLOTS). LPR lanes x 16B
// uint4 per row; shfl_xor cross-slot reduction; fp32 bias/relu/store.

template <int OC, int U, bool RELU>
__global__ __launch_bounds__(256) void k_aggp(const uint4* __restrict__ hs,
                                              const int* __restrict__ csr_row,
                                              const int* __restrict__ offs,
                                              const float* __restrict__ dinv,
                                              const float* __restrict__ bias,
                                              float* __restrict__ out) {
    constexpr int LPR = (OC * 2) / 16;   // 16 (OC=128) or 8 (OC=64)
    constexpr int SLOTS = 64 / LPR;      // 4 or 8
    const int lane = threadIdx.x & 63;
    const int sub = lane / LPR;
    const int q = lane % LPR;
    const int wid = (blockIdx.x * 4) + (threadIdx.x >> 6);
    const int nwaves = gridDim.x * 4;

    for (int t0 = wid * 2; t0 < N_NODES; t0 += nwaves * 2) {
        const int t1 = t0 + 1;  // N_NODES even -> always valid
        const int s0 = offs[t0], e0 = offs[t0 + 1];
        const int s1 = offs[t1], e1 = offs[t1 + 1];
        float a0[8] = {}, a1[8] = {};
        int j0 = s0, j1 = s1;
        while (j0 < e0 || j1 < e1) {
            int r0[U], r1[U];
#pragma unroll
            for (int u = 0; u < U; ++u) {
                int jj = j0 + u * SLOTS + sub;
                r0[u] = (jj < e0) ? __builtin_nontemporal_load(csr_row + jj) : -1;
            }
#pragma unroll
            for (int u = 0; u < U; ++u) {
                int jj = j1 + u * SLOTS + sub;
                r1[u] = (jj < e1) ? __builtin_nontemporal_load(csr_row + jj) : -1;
            }
            uint4 v0[U], v1[U];
#pragma unroll
            for (int u = 0; u < U; ++u) {
                v0[u] = make_uint4(0u, 0u, 0u, 0u);
                if (r0[u] >= 0) v0[u] = hs[(size_t)r0[u] * LPR + q];
            }
#pragma unroll
            for (int u = 0; u < U; ++u) {
                v1[u] = make_uint4(0u, 0u, 0u, 0u);
                if (r1[u] >= 0) v1[u] = hs[(size_t)r1[u] * LPR + q];
            }
#pragma unroll
            for (int u = 0; u < U; ++u) {
                a0[0] += blo(v0[u].x); a0[1] += bhi(v0[u].x);
                a0[2] += blo(v0[u].y); a0[3] += bhi(v0[u].y);
                a0[4] += blo(v0[u].z); a0[5] += bhi(v0[u].z);
                a0[6] += blo(v0[u].w); a0[7] += bhi(v0[u].w);
                a1[0] += blo(v1[u].x); a1[1] += bhi(v1[u].x);
                a1[2] += blo(v1[u].y); a1[3] += bhi(v1[u].y);
                a1[4] += blo(v1[u].z); a1[5] += bhi(v1[u].z);
                a1[6] += blo(v1[u].w); a1[7] += bhi(v1[u].w);
            }
            j0 += U * SLOTS;
            j1 += U * SLOTS;
        }
#pragma unroll
        for (int off = 32; off >= LPR; off >>= 1) {
#pragma unroll
            for (int i = 0; i < 8; ++i) {
                a0[i] += __shfl_xor(a0[i], off);
                a1[i] += __shfl_xor(a1[i], off);
            }
        }
        if (lane < LPR) {
            const float4 b0 = *reinterpret_cast<const float4*>(bias + lane * 8);
            const float4 b1 = *reinterpret_cast<const float4*>(bias + lane * 8 + 4);
            const float d0 = dinv[t0], d1 = dinv[t1];
            float4 r0, r1, r2, r3;
            r0.x = a0[0] * d0 + b0.x; r0.y = a0[1] * d0 + b0.y;
            r0.z = a0[2] * d0 + b0.z; r0.w = a0[3] * d0 + b0.w;
            r1.x = a0[4] * d0 + b1.x; r1.y = a0[5] * d0 + b1.y;
            r1.z = a0[6] * d0 + b1.z; r1.w = a0[7] * d0 + b1.w;
            r2.x = a1[0] * d1 + b0.x; r2.y = a1[1] * d1 + b0.y;
            r2.z = a1[2] * d1 + b0.z; r2.w = a1[3] * d1 + b0.w;
            r3.x = a1[4] * d1 + b1.x; r3.y = a1[5] * d1 + b1.y;
            r3.z = a1[6] * d1 + b1.z; r3.w = a1[7] * d1 + b1.w;
            if (RELU) {
                r0.x = fmaxf(r0.x, 0.f); r0.y = fmaxf(r0.y, 0.f);
                r0.z = fmaxf(r0.z, 0.f); r0.w = fmaxf(r0.w, 0.f);
                r1.x = fmaxf(r1.x, 0.f); r1.y = fmaxf(r1.y, 0.f);
                r1.z = fmaxf(r1.z, 0.f); r1.w = fmaxf(r1.w, 0.f);
                r2.x = fmaxf(r2.x, 0.f); r2.y = fmaxf(r2.y, 0.f);
                r2.z = fmaxf(r2.z, 0.f); r2.w = fmaxf(r2.w, 0.f);
                r3.x = fmaxf(r3.x, 0.f); r3.y = fmaxf(r3.y, 0.f);
                r3.z = fmaxf(r3.z, 0.f); r3.w = fmaxf(r3.w, 0.f);
            }
            float* p0 = out + (size_t)t0 * OC + lane * 8;
            float* p1 = out + (size_t)t1 * OC + lane * 8;
            *reinterpret_cast<float4*>(p0) = r0;
            *reinterpret_cast<float4*>(p0 + 4) = r1;
            *reinterpret_cast<float4*>(p1) = r2;
            *reinterpret_cast<float4*>(p1 + 4) = r3;
        }
    }
}

// ---------------- launch ----------------

extern "C" void kernel_launch(void* const* d_in, const int* in_sizes, int n_in,
                              void* d_out, int out_size, void* d_ws, size_t ws_size,
                              hipStream_t stream) {
    const float* x  = (const float*)d_in[0];
    const int*   ei = (const int*)d_in[1];
    const float* W1 = (const float*)d_in[2];
    const float* b1 = (const float*)d_in[3];
    const float* W2 = (const float*)d_in[4];
    const float* b2 = (const float*)d_in[5];
    float* out = (float*)d_out;

    char* w = (char*)d_ws;
    auto alloc = [&](size_t bytes) {
        void* p = (void*)w;
        w += (bytes + 255) & ~(size_t)255;
        return p;
    };
    float* dinv    = (float*)alloc((size_t)N_NODES * 4);
    int*   offs    = (int*)alloc((size_t)(N_NODES + 1) * 4);
    int*   bcur    = (int*)alloc((size_t)NBUCK * 4);
    int*   bbase   = (int*)alloc(256 * 4);
    unsigned* staging = (unsigned*)alloc((size_t)NBUCK * BCAP * 4); // 8.0 MB
    int*   csr_row = (int*)alloc((size_t)N_EDGES * 4);
    unsigned short* hs1 = (unsigned short*)alloc((size_t)N_NODES * HIDC * 2); // bf16
    float* h       = (float*)alloc((size_t)N_NODES * HIDC * 4);
    unsigned short* hs2 = hs1; // bf16, reuse (hs1 dead after layer-1 agg)

    // CSR + norm build (fixed-capacity buckets; no pre-count)
    k_binit<<<1, 256, 0, stream>>>(bcur);
    k_bin<<<NBINBLK, 256, 0, stream>>>(ei, bcur, staging);
    k_bucket_scan<<<1, 256, 0, stream>>>(bcur, bbase, offs);
    k_scatter2<<<NBUCK, 256, 0, stream>>>(staging, bcur, bbase, offs, dinv, csr_row);

    // layer 1: 64 nodes x 128 outs per block
    k_gemm3<64, HIDC><<<(N_NODES + 63) / 64, 256, 0, stream>>>(x, W1, dinv, hs1);
    k_aggp<HIDC, 4, true><<<2048, 256, 0, stream>>>((const uint4*)hs1, csr_row, offs, dinv, b1, h);

    // layer 2: 128 nodes x 64 outs per block
    k_gemm3<128, OUTC><<<(N_NODES + 127) / 128, 256, 0, stream>>>(h, W2, dinv, hs2);
    k_aggp<OUTC, 2, false><<<2048, 256, 0, stream>>>((const uint4*)hs2, csr_row, offs, dinv, b2, out);
}